// Round 6
// baseline (991.838 us; speedup 1.0000x reference)
//
#include <hip/hip_runtime.h>
#include <cstdint>
#include <cstddef>

#define M_DIM 4096
#define N_DIM 16384
#define K_DIM 4096
#define NBLK_Q 128

#define BM 128
#define BN 256
#define BK 32
#define KTILES (K_DIM / BK)  // 128
#define BUFB 24576           // one LDS buffer: A 8KB (8 frags) + B 16KB (16 frags)

typedef __bf16 bf16x8 __attribute__((ext_vector_type(8)));
typedef float f32x4 __attribute__((ext_vector_type(4)));
typedef unsigned short u16x8 __attribute__((ext_vector_type(8)));

__device__ __forceinline__ unsigned short f2bf(float f) {
  unsigned int u = __builtin_bit_cast(unsigned int, f);
  u += 0x7fffu + ((u >> 16) & 1u);
  return (unsigned short)(u >> 16);
}

__device__ __forceinline__ void async_copy16(const void* g, void* l) {
  __builtin_amdgcn_global_load_lds((__attribute__((address_space(1))) void*)g,
                                   (__attribute__((address_space(3))) void*)l,
                                   16, 0, 0);
}

// fence-ful barrier: HW s_barrier + compiler memory clobber (LDS ops can't be
// hoisted/sunk across). Does NOT drain vmcnt/lgkm (counted-vmcnt pipeline).
#define BARRIER() asm volatile("s_barrier" ::: "memory")

// ---------------- pre-pass 1: x fp32 -> bf16 (A matrix [M][K]) ----------------
__global__ __launch_bounds__(256) void cvt_x_bf16(const float4* __restrict__ x,
                                                  ushort4* __restrict__ A) {
  int tid = blockIdx.x * 256 + threadIdx.x;
  float4 v = x[tid];
  ushort4 o;
  o.x = f2bf(v.x); o.y = f2bf(v.y); o.z = f2bf(v.z); o.w = f2bf(v.w);
  A[tid] = o;
}

// ------------- pre-pass 2: dequantize qs int32 + scales -> W bf16 [N][K] -------------
__global__ __launch_bounds__(256) void dequant_w(const int* __restrict__ qs,
                                                 const float* __restrict__ scales,
                                                 unsigned short* __restrict__ W) {
  size_t tid = (size_t)blockIdx.x * 256 + threadIdx.x;
  size_t e = tid * 8;
  size_t o = e >> 12;
  int nb = ((int)(e & 4095)) >> 5;
  float s = scales[o * NBLK_Q + nb];
  const int4* q = (const int4*)(qs + e);
  int4 q0 = q[0], q1 = q[1];
  u16x8 out;
  out[0] = f2bf(s * (float)q0.x);
  out[1] = f2bf(s * (float)q0.y);
  out[2] = f2bf(s * (float)q0.z);
  out[3] = f2bf(s * (float)q0.w);
  out[4] = f2bf(s * (float)q1.x);
  out[5] = f2bf(s * (float)q1.y);
  out[6] = f2bf(s * (float)q1.z);
  out[7] = f2bf(s * (float)q1.w);
  *(u16x8*)(W + e) = out;
}

// ---------------- main GEMM: C[M][N] = A[M][K] * Bt[N][K]^T + bias ----------------
// 128x256 tile, BK=32, 8 waves (2M x 4N), per-wave 64x64 (4x4 frags, 16x16x32
// MFMA) -> acc = 64 VGPR; __launch_bounds__(512,4) caps VGPR at 128 -> 4
// waves/SIMD. LDS = 3 x 24KB buffers = 72KB -> 2 INDEPENDENT blocks/CU
// (16 waves/CU): cross-block overlap covers barrier/lgkm stalls (m114/m97).
// Per K-step: {vmcnt(3) [batch kt landed]; barrier; 8 ds_read_b128 (base+imm);
// stage batch kt+2 (3 x global_load_lds, 24KB/block); setprio(1); 16 MFMA;
// setprio(0)}. One barrier per step; vmcnt never 0 in loop.
// Buffer rotation: read buf kt%3, write buf (kt+2)%3 — safe: last reads of the
// write target (iter kt-1) completed before their MFMAs, which precede the
// barrier the writer passed. Tail: batch index clamped to 127 — duplicates
// land in rotating buffers that are never read again.
// LDS layout (0 bank conflicts, R1-R5 proven): frag-contiguous, frag f of A at
// f*1024, frag f of B at 8192+f*1024; element (row r, k 8g+j) at byte
// r*16+g*256+j*2; MFMA lane λ reads its 16B at byte λ*16.
__global__ __launch_bounds__(512, 4) void gemm_bt_bias(
    const unsigned short* __restrict__ A,   // [M][K] bf16
    const unsigned short* __restrict__ Bt,  // [N][K] bf16
    const float* __restrict__ bias,         // [N]
    float* __restrict__ C) {                // [M][N] fp32
  __shared__ char lds[3 * BUFB];  // 72KB

  const int tid = threadIdx.x;
  const int w = tid >> 6;   // wave 0..7
  const int l = tid & 63;
  const int wm = w >> 2;    // 0..1 (M half)
  const int wn = w & 3;     // 0..3 (N quarter)
  const int sr = l & 15;
  const int sg = l >> 4;

  // XCD-chunked bijective grid (nwg=2048), mtile fastest within chunk:
  // per XCD ~2 ntiles x 32 mtiles concurrent -> W slice L2-resident, A L3.
  const int bid = blockIdx.x;
  const int wgid = (bid & 7) * 256 + (bid >> 3);
  const int mtile = wgid & 31;   // 32 mtiles (M/128)
  const int ntile = wgid >> 5;   // 64 ntiles (N/256)
  const int brow = mtile * BM;
  const int bcol = ntile * BN;

  // staging: 24 frags (A:0..7, B:8..23); wave w stages frags 3w..3w+2
  const unsigned short* src[3];
  int ldsoff[3];
#pragma unroll
  for (int i = 0; i < 3; ++i) {
    const int f = 3 * w + i;
    if (f < 8) {
      src[i] = A + (size_t)(brow + f * 16 + sr) * K_DIM + sg * 8;
      ldsoff[i] = f * 1024;
    } else {
      src[i] = Bt + (size_t)(bcol + (f - 8) * 16 + sr) * K_DIM + sg * 8;
      ldsoff[i] = 8192 + (f - 8) * 1024;
    }
  }

  f32x4 acc[4][4] = {};

  // prologue: stage batches 0 -> buf0, 1 -> buf1 (6 loads/thread outstanding)
#pragma unroll
  for (int t = 0; t < 2; ++t)
#pragma unroll
    for (int i = 0; i < 3; ++i)
      async_copy16(src[i] + t * BK, lds + t * BUFB + ldsoff[i] + l * 16);

  int br = 0;       // read buffer  = kt % 3
  int bw = 2;       // write buffer = (kt+2) % 3
  for (int kt = 0; kt < KTILES; ++kt) {
    asm volatile("s_waitcnt vmcnt(3)" ::: "memory");  // batch kt landed (per-wave)
    BARRIER();                                        // ... for ALL waves

    const char* rb = lds + br * BUFB + l * 16;
    const char* rbA = rb + wm * 4096;
    const char* rbB = rb + 8192 + wn * 4096;
    bf16x8 a[4], b[4];
#pragma unroll
    for (int i = 0; i < 4; ++i) a[i] = *(const bf16x8*)(rbA + i * 1024);
#pragma unroll
    for (int j = 0; j < 4; ++j) b[j] = *(const bf16x8*)(rbB + j * 1024);

    // stage batch kt+2 into bw (clamped tail: duplicates land in unread bufs)
    {
      const int qa = (kt + 2 > KTILES - 1) ? (KTILES - 1) : (kt + 2);
      char* dstb = lds + bw * BUFB + l * 16;
#pragma unroll
      for (int i = 0; i < 3; ++i)
        async_copy16(src[i] + qa * BK, dstb + ldsoff[i]);
    }

    __builtin_amdgcn_s_setprio(1);
#pragma unroll
    for (int i = 0; i < 4; ++i)
#pragma unroll
      for (int j = 0; j < 4; ++j)
        acc[i][j] = __builtin_amdgcn_mfma_f32_16x16x32_bf16(a[i], b[j], acc[i][j], 0, 0, 0);
    __builtin_amdgcn_s_setprio(0);

    br = (br == 2) ? 0 : br + 1;
    bw = (bw == 2) ? 0 : bw + 1;
  }

  asm volatile("s_waitcnt vmcnt(0)" ::: "memory");  // drain DMA before exit

  // epilogue: C/D layout col = lane&15, row = (lane>>4)*4 + t
#pragma unroll
  for (int j = 0; j < 4; ++j) {
    const int col = bcol + wn * 64 + j * 16 + sr;
    const float bv = bias[col];
#pragma unroll
    for (int i = 0; i < 4; ++i) {
      const int row = brow + wm * 64 + i * 16 + sg * 4;
#pragma unroll
      for (int t = 0; t < 4; ++t) {
        C[(size_t)(row + t) * N_DIM + col] = acc[i][j][t] + bv;
      }
    }
  }
}

// ---------------- fallback (ws too small): exact fp32, slow but correct ----------------
__global__ void naive_gemm(const float* __restrict__ x, const int* __restrict__ qs,
                           const float* __restrict__ scales, const float* __restrict__ bias,
                           float* __restrict__ y) {
  size_t idx = (size_t)blockIdx.x * 256 + threadIdx.x;
  if (idx >= (size_t)M_DIM * N_DIM) return;
  int o = (int)(idx % N_DIM);
  size_t m = idx / N_DIM;
  const float* xr = x + m * K_DIM;
  const int* q = qs + (size_t)o * K_DIM;
  const float* sc = scales + (size_t)o * NBLK_Q;
  float sum = 0.f;
  for (int nb = 0; nb < NBLK_Q; ++nb) {
    float s = sc[nb];
    float bs = 0.f;
#pragma unroll 8
    for (int b = 0; b < 32; ++b) bs += xr[nb * 32 + b] * (float)q[nb * 32 + b];
    sum += s * bs;
  }
  y[idx] = sum + bias[o];
}

extern "C" void kernel_launch(void* const* d_in, const int* in_sizes, int n_in,
                              void* d_out, int out_size, void* d_ws, size_t ws_size,
                              hipStream_t stream) {
  const float* x = (const float*)d_in[0];
  const int* qs = (const int*)d_in[1];
  const float* scales = (const float*)d_in[2];
  const float* bias = (const float*)d_in[3];
  float* y = (float*)d_out;

  const size_t A_bytes = (size_t)M_DIM * K_DIM * 2;  // 32 MB
  const size_t W_bytes = (size_t)N_DIM * K_DIM * 2;  // 128 MB

  if (ws_size < A_bytes + W_bytes) {
    size_t total = (size_t)M_DIM * N_DIM;
    naive_gemm<<<(unsigned)((total + 255) / 256), 256, 0, stream>>>(x, qs, scales, bias, y);
    return;
  }

  unsigned short* A = (unsigned short*)d_ws;
  unsigned short* W = (unsigned short*)((char*)d_ws + A_bytes);

  cvt_x_bf16<<<(M_DIM * K_DIM / 4) / 256, 256, 0, stream>>>((const float4*)x, (ushort4*)A);
  dequant_w<<<(int)(((size_t)N_DIM * K_DIM / 8) / 256), 256, 0, stream>>>(qs, scales, W);
  gemm_bt_bias<<<(M_DIM / BM) * (N_DIM / BN), 512, 0, stream>>>(A, W, bias, y);
}

// Round 7
// 841.308 us; speedup vs baseline: 1.1789x; 1.1789x over previous
//
#include <hip/hip_runtime.h>
#include <cstdint>
#include <cstddef>

#define M_DIM 4096
#define N_DIM 16384
#define K_DIM 4096
#define NBLK_Q 128

#define BM 256
#define BN 256
#define BK 64
#define KTILES (K_DIM / BK)   // 64
#define NGROUPS (KTILES * 4)  // 256 16KB half-tile groups

typedef __bf16 bf16x8 __attribute__((ext_vector_type(8)));
typedef float f32x4 __attribute__((ext_vector_type(4)));
typedef unsigned short u16x8 __attribute__((ext_vector_type(8)));

__device__ __forceinline__ unsigned short f2bf(float f) {
  unsigned int u = __builtin_bit_cast(unsigned int, f);
  u += 0x7fffu + ((u >> 16) & 1u);
  return (unsigned short)(u >> 16);
}

__device__ __forceinline__ void async_copy16(const void* g, void* l) {
  __builtin_amdgcn_global_load_lds((__attribute__((address_space(1))) void*)g,
                                   (__attribute__((address_space(3))) void*)l,
                                   16, 0, 0);
}

// Sync idiom (NO memory clobbers anywhere in the K-loop!):
//  - inline asm with ::: "memory" makes the waitcnt legalizer treat the asm as
//    a memory op and conservatively DRAIN vmcnt/lgkm before it — silently
//    converting the counted-vmcnt pipeline into drain-0 (the m218 slow regime).
//  - s_barrier via builtin (IntrNoMem: no drains), motion-fenced on both sides
//    with sched_barrier(0) (compile-time only).
//  - vmcnt waits as clobber-free volatile asm: register-only => legalizer
//    ignores it; volatile keeps program order vs global_load_lds intrinsics.
#define SFENCE() __builtin_amdgcn_sched_barrier(0)
#define BAR() __builtin_amdgcn_s_barrier()
#define WAITVM(n) asm volatile("s_waitcnt vmcnt(" #n ")")

// ---------------- pre-pass 1: x fp32 -> bf16 (A matrix [M][K]) ----------------
__global__ __launch_bounds__(256) void cvt_x_bf16(const float4* __restrict__ x,
                                                  ushort4* __restrict__ A) {
  int tid = blockIdx.x * 256 + threadIdx.x;
  float4 v = x[tid];
  ushort4 o;
  o.x = f2bf(v.x); o.y = f2bf(v.y); o.z = f2bf(v.z); o.w = f2bf(v.w);
  A[tid] = o;
}

// ------------- pre-pass 2: dequantize qs int32 + scales -> W bf16 [N][K] -------------
__global__ __launch_bounds__(256) void dequant_w(const int* __restrict__ qs,
                                                 const float* __restrict__ scales,
                                                 unsigned short* __restrict__ W) {
  size_t tid = (size_t)blockIdx.x * 256 + threadIdx.x;
  size_t e = tid * 8;
  size_t o = e >> 12;
  int nb = ((int)(e & 4095)) >> 5;
  float s = scales[o * NBLK_Q + nb];
  const int4* q = (const int4*)(qs + e);
  int4 q0 = q[0], q1 = q[1];
  u16x8 out;
  out[0] = f2bf(s * (float)q0.x);
  out[1] = f2bf(s * (float)q0.y);
  out[2] = f2bf(s * (float)q0.z);
  out[3] = f2bf(s * (float)q0.w);
  out[4] = f2bf(s * (float)q1.x);
  out[5] = f2bf(s * (float)q1.y);
  out[6] = f2bf(s * (float)q1.z);
  out[7] = f2bf(s * (float)q1.w);
  *(u16x8*)(W + e) = out;
}

// ---------------- main GEMM: C[M][N] = A[M][K] * Bt[N][K]^T + bias ----------------
// 256x256, BK=64, 8 waves (2Mx4N), per-wave 128x64, 16x16x32 MFMA, 4 phases/K-tile.
// Phase: {ds_read this phase's frags (pre-barrier, hide under prev MFMA drain);
// stage; [vmcnt(2) at P3 only]; SFENCE; BAR; SFENCE; setprio(1); 16 MFMA
// (compiler places fine-grained lgkm waits); setprio(0); SFENCE; BAR; SFENCE}.
// Counted vmcnt NEVER 0 in the loop; up to 8 loads in flight across barriers.
// Stage cadence fixed (tail clamped: duplicate stages rewrite identical bytes),
// so vmcnt(2)@P3 always means "tile kt+1 fully landed"; 2 barriers follow
// before its P0 reads (covers all waves). LDS: 2 x 64KB fragment-contiguous
// buffers (1KB frags, 0 bank conflicts); groups g0=A.ks0 g1=A.ks1 g2=B.ks0
// g3=B.ks1; wave w stages frags 2w,2w+1 of each group (wave-uniform dest +
// lane*16, pre-swizzled global source). Safety of in-loop writes:
// P0/P1 stages hit the OTHER buffer; P3's stage (tile kt+2 g0 -> current
// buffer) is issued after P2's closing barrier = after all waves' last reads
// of that region.
__global__ __launch_bounds__(512, 2) void gemm_bt_bias(
    const unsigned short* __restrict__ A,   // [M][K] bf16
    const unsigned short* __restrict__ Bt,  // [N][K] bf16
    const float* __restrict__ bias,         // [N]
    float* __restrict__ C) {                // [M][N] fp32
  __shared__ char lds[131072];  // 2 x 64KB

  const int tid = threadIdx.x;
  const int w = tid >> 6;   // wave 0..7
  const int l = tid & 63;
  const int wm = w >> 2;    // M half
  const int wn = w & 3;     // N quarter
  const int sr = l & 15;
  const int sg = l >> 4;

  // XCD-chunked bijective grid mapping, mtile fastest
  const int bid = blockIdx.x;
  const int wgid = (bid & 7) * 128 + (bid >> 3);
  const int mtile = wgid & 15;
  const int ntile = wgid >> 4;
  const int brow = mtile * BM;
  const int bcol = ntile * BN;

  // precomputed per-thread staging bases (element offsets into A / Bt)
  const size_t offA = (size_t)(brow + (w * 2) * 16 + sr) * K_DIM + sg * 8;
  const size_t offB = (size_t)(bcol + (w * 2) * 16 + sr) * K_DIM + sg * 8;
  char* const ldsbase = lds + w * 2048 + l * 16;

  auto stage = [&](int q) {
    q = (q > NGROUPS - 1) ? (NGROUPS - 1) : q;  // clamp: fixed issue cadence
    const int kt_s = q >> 2;
    const int g = q & 3;
    const int kof = kt_s * BK + (g & 1) * 32;
    const unsigned short* src = (g < 2) ? (A + offA + kof) : (Bt + offB + kof);
    char* dst = ldsbase + (kt_s & 1) * 65536 + g * 16384;
    async_copy16(src, dst);
    async_copy16(src + 16 * K_DIM, dst + 1024);
  };

  f32x4 acc[8][4] = {};
  bf16x8 pa[2][4];  // A fragments for current ih-half (ks, i)
  bf16x8 b[2][4];   // B fragments for whole K-tile (ks, j)

  // prologue: stage tile0 g0-g3 + tile1 g0; wait tile0 (leave tile1.g0 in flight)
#pragma unroll
  for (int q = 0; q < 5; ++q) stage(q);
  WAITVM(2);
  SFENCE(); BAR(); SFENCE();

  for (int kt = 0; kt < KTILES; ++kt) {
    const char* bb = lds + (kt & 1) * 65536;

    // ---- P0: quadrant (ih0, jh0) ----
#pragma unroll
    for (int s = 0; s < 2; ++s) {
#pragma unroll
      for (int i = 0; i < 4; ++i)
        pa[s][i] = *(const bf16x8*)(bb + (s * 16 + wm * 8 + i) * 1024 + l * 16);
#pragma unroll
      for (int j = 0; j < 2; ++j)
        b[s][j] = *(const bf16x8*)(bb + 32768 + (s * 16 + wn * 4 + j) * 1024 + l * 16);
    }
    stage(4 * kt + 5);
    stage(4 * kt + 6);
    SFENCE(); BAR(); SFENCE();
    __builtin_amdgcn_s_setprio(1);
#pragma unroll
    for (int i = 0; i < 4; ++i)
#pragma unroll
      for (int j = 0; j < 2; ++j) {
        acc[i][j] = __builtin_amdgcn_mfma_f32_16x16x32_bf16(pa[0][i], b[0][j], acc[i][j], 0, 0, 0);
        acc[i][j] = __builtin_amdgcn_mfma_f32_16x16x32_bf16(pa[1][i], b[1][j], acc[i][j], 0, 0, 0);
      }
    __builtin_amdgcn_s_setprio(0);
    SFENCE(); BAR(); SFENCE();

    // ---- P1: quadrant (ih0, jh1) ----
#pragma unroll
    for (int s = 0; s < 2; ++s)
#pragma unroll
      for (int j = 0; j < 2; ++j)
        b[s][2 + j] = *(const bf16x8*)(bb + 32768 + (s * 16 + wn * 4 + 2 + j) * 1024 + l * 16);
    stage(4 * kt + 7);
    SFENCE(); BAR(); SFENCE();
    __builtin_amdgcn_s_setprio(1);
#pragma unroll
    for (int i = 0; i < 4; ++i)
#pragma unroll
      for (int j = 0; j < 2; ++j) {
        acc[i][2 + j] = __builtin_amdgcn_mfma_f32_16x16x32_bf16(pa[0][i], b[0][2 + j], acc[i][2 + j], 0, 0, 0);
        acc[i][2 + j] = __builtin_amdgcn_mfma_f32_16x16x32_bf16(pa[1][i], b[1][2 + j], acc[i][2 + j], 0, 0, 0);
      }
    __builtin_amdgcn_s_setprio(0);
    SFENCE(); BAR(); SFENCE();

    // ---- P2: quadrant (ih1, jh0) ----
#pragma unroll
    for (int s = 0; s < 2; ++s)
#pragma unroll
      for (int i = 0; i < 4; ++i)
        pa[s][i] = *(const bf16x8*)(bb + (s * 16 + wm * 8 + 4 + i) * 1024 + l * 16);
    SFENCE(); BAR(); SFENCE();
    __builtin_amdgcn_s_setprio(1);
#pragma unroll
    for (int i = 0; i < 4; ++i)
#pragma unroll
      for (int j = 0; j < 2; ++j) {
        acc[4 + i][j] = __builtin_amdgcn_mfma_f32_16x16x32_bf16(pa[0][i], b[0][j], acc[4 + i][j], 0, 0, 0);
        acc[4 + i][j] = __builtin_amdgcn_mfma_f32_16x16x32_bf16(pa[1][i], b[1][j], acc[4 + i][j], 0, 0, 0);
      }
    __builtin_amdgcn_s_setprio(0);
    SFENCE(); BAR(); SFENCE();  // bar2(P2): all waves done reading this buffer's g0/g1

    // ---- P3: quadrant (ih1, jh1) ----
    stage(4 * kt + 8);  // tile kt+2 g0 -> current buffer; safe post bar2(P2)
    WAITVM(2);          // tile kt+1 fully landed (per-wave; barriers globalize)
    SFENCE(); BAR(); SFENCE();
    __builtin_amdgcn_s_setprio(1);
#pragma unroll
    for (int i = 0; i < 4; ++i)
#pragma unroll
      for (int j = 0; j < 2; ++j) {
        acc[4 + i][2 + j] = __builtin_amdgcn_mfma_f32_16x16x32_bf16(pa[0][i], b[0][2 + j], acc[4 + i][2 + j], 0, 0, 0);
        acc[4 + i][2 + j] = __builtin_amdgcn_mfma_f32_16x16x32_bf16(pa[1][i], b[1][2 + j], acc[4 + i][2 + j], 0, 0, 0);
      }
    __builtin_amdgcn_s_setprio(0);
    SFENCE(); BAR(); SFENCE();
  }

  WAITVM(0);  // drain DMA before exit
  SFENCE();

  // epilogue: C/D layout col = lane&15, row = (lane>>4)*4 + t
#pragma unroll
  for (int j = 0; j < 4; ++j) {
    const int col = bcol + wn * 64 + j * 16 + sr;
    const float bv = bias[col];
#pragma unroll
    for (int i = 0; i < 8; ++i) {
      const int row = brow + wm * 128 + i * 16 + sg * 4;
#pragma unroll
      for (int t = 0; t < 4; ++t) {
        C[(size_t)(row + t) * N_DIM + col] = acc[i][j][t] + bv;
      }
    }
  }
}

// ---------------- fallback (ws too small): exact fp32, slow but correct ----------------
__global__ void naive_gemm(const float* __restrict__ x, const int* __restrict__ qs,
                           const float* __restrict__ scales, const float* __restrict__ bias,
                           float* __restrict__ y) {
  size_t idx = (size_t)blockIdx.x * 256 + threadIdx.x;
  if (idx >= (size_t)M_DIM * N_DIM) return;
  int o = (int)(idx % N_DIM);
  size_t m = idx / N_DIM;
  const float* xr = x + m * K_DIM;
  const int* q = qs + (size_t)o * K_DIM;
  const float* sc = scales + (size_t)o * NBLK_Q;
  float sum = 0.f;
  for (int nb = 0; nb < NBLK_Q; ++nb) {
    float s = sc[nb];
    float bs = 0.f;
#pragma unroll 8
    for (int b = 0; b < 32; ++b) bs += xr[nb * 32 + b] * (float)q[nb * 32 + b];
    sum += s * bs;
  }
  y[idx] = sum + bias[o];
}

extern "C" void kernel_launch(void* const* d_in, const int* in_sizes, int n_in,
                              void* d_out, int out_size, void* d_ws, size_t ws_size,
                              hipStream_t stream) {
  const float* x = (const float*)d_in[0];
  const int* qs = (const int*)d_in[1];
  const float* scales = (const float*)d_in[2];
  const float* bias = (const float*)d_in[3];
  float* y = (float*)d_out;

  const size_t A_bytes = (size_t)M_DIM * K_DIM * 2;  // 32 MB
  const size_t W_bytes = (size_t)N_DIM * K_DIM * 2;  // 128 MB

  if (ws_size < A_bytes + W_bytes) {
    size_t total = (size_t)M_DIM * N_DIM;
    naive_gemm<<<(unsigned)((total + 255) / 256), 256, 0, stream>>>(x, qs, scales, bias, y);
    return;
  }

  unsigned short* A = (unsigned short*)d_ws;
  unsigned short* W = (unsigned short*)((char*)d_ws + A_bytes);

  cvt_x_bf16<<<(M_DIM * K_DIM / 4) / 256, 256, 0, stream>>>((const float4*)x, (ushort4*)A);
  dequant_w<<<(int)(((size_t)N_DIM * K_DIM / 8) / 256), 256, 0, stream>>>(qs, scales, W);
  gemm_bt_bias<<<(M_DIM / BM) * (N_DIM / BN), 512, 0, stream>>>(A, W, bias, y);
}